// Round 1
// 288.805 us; speedup vs baseline: 1.0255x; 1.0255x over previous
//
#include <hip/hip_runtime.h>
#include <math.h>

#define QSEQ 33600

typedef __attribute__((ext_vector_type(8))) short short8;
typedef __attribute__((ext_vector_type(4))) float floatx4;
typedef unsigned short ushort_t;

static __device__ __forceinline__ ushort_t f2bf(float f) {
  unsigned u = __float_as_uint(f);
  return (ushort_t)((u + 0x7FFF + ((u >> 16) & 1)) >> 16);
}

// async global->LDS, 16B per lane; lds dest = wave-uniform base + lane*16
static __device__ __forceinline__ void gload_lds16(const void* g, void* l) {
  __builtin_amdgcn_global_load_lds((__attribute__((address_space(1))) void*)g,
                                   (__attribute__((address_space(3))) void*)l, 16, 0, 0);
}

// ---------------------------------------------------------------------------
// MFMA GEMM body, BM=96 (33600 = 350*96), BN=128, BK=64, K=256.
// 256 thr = 4 waves (2x2), wave tile 48x64 (3x4 frags of 16x16x32 bf16).
// LDS: As 96x64 bf16 | Bs 128x64 bf16, chunk-XOR swizzle (slot (row,s) holds
// global 16B-chunk s^(row&7)).
// B is staged from *fp32* weights with inline bf16 convert (no pre-pass).
// B row select: global row < bsplit -> B1[row], else B2[row-bsplit] (clamped).
// ASRC: 0 = A bf16 via global_load_lds; 1 = A fp32 cvt; 2 = fp32 A1+A2 add.
// MODE: 0 = fp32 C1[M,N]; 1 = bf16 head-major [col>>5][row][col&31];
//       2 = N=288 merged: cols<96 logits -> fused softmax -> C1 [Q,96] fp32,
//           cols [96,288) -> C2 [Q,192] fp32 (+b2).
// ---------------------------------------------------------------------------
template <int ASRC, int MODE>
static __device__ __forceinline__ void gemm_body(
    const int bx, const int by,
    const float* __restrict__ A1, const float* __restrict__ A2,
    const ushort_t* __restrict__ Ab,
    const float* __restrict__ B1, const float* __restrict__ B2, const int bsplit,
    const float* __restrict__ b1, const float* __restrict__ b2,
    void* __restrict__ C1, float* __restrict__ C2, const int N,
    ushort_t* smem) {
  ushort_t* As = smem;         // 6144 ushorts
  ushort_t* Bs = smem + 6144;  // 8192 ushorts

  const int tid = threadIdx.x;
  const int m0 = by * 96;
  const int n0 = bx * 128;
  const int wv = tid >> 6, lane = tid & 63;
  const int wm = wv >> 1, wn = wv & 1;
  const int l16 = lane & 15, quad = lane >> 4;
  const int l8 = l16 & 7;

  // --- A staging descriptors: 768 chunks (96 rows x 8), 3 per thread ---
  const float* gAf[3];
  const float* gAf2[3];
  const ushort_t* gAb[3];
  ushort_t* lA[3];
#pragma unroll
  for (int i = 0; i < 3; ++i) {
    const int c = tid + i * 256;
    const int row = c >> 3, s = c & 7;
    if (ASRC == 0) {
      gAb[i] = Ab + (size_t)(m0 + row) * 256 + ((s ^ (row & 7)) * 8);
      lA[i] = As + (wv * 64 + i * 256) * 8;  // wave-uniform base, lane-linear
    } else {
      gAf[i] = A1 + (size_t)(m0 + row) * 256 + s * 8;
      if (ASRC == 2) gAf2[i] = A2 + (size_t)(m0 + row) * 256 + s * 8;
      lA[i] = As + row * 64 + (s ^ (row & 7)) * 8;
    }
  }
  // --- B staging: 1024 chunks (128 rows x 8), 4 per thread, fp32 src ---
  const float* gBf[4];
  ushort_t* lBf[4];
#pragma unroll
  for (int j = 0; j < 4; ++j) {
    const int c = tid + j * 256;
    const int row = c >> 3, s = c & 7;
    const int grow = n0 + row;
    const float* bsrc;
    int r2;
    if (grow < bsplit) {
      bsrc = B1;
      r2 = grow;
    } else {
      bsrc = B2;
      r2 = grow - bsplit;
      const int rmax = N - bsplit - 1;
      if (r2 > rmax) r2 = rmax;  // clamp: garbage cols, stores guarded
    }
    gBf[j] = bsrc + (size_t)r2 * 256 + s * 8;
    lBf[j] = Bs + row * 64 + (s ^ (row & 7)) * 8;
  }

  floatx4 acc[3][4];
#pragma unroll
  for (int i = 0; i < 3; ++i)
#pragma unroll
    for (int j = 0; j < 4; ++j) acc[i][j] = (floatx4)(0.f);

  for (int k0 = 0; k0 < 256; k0 += 64) {
    // ---- stage A ----
    if (ASRC == 0) {
#pragma unroll
      for (int i = 0; i < 3; ++i) gload_lds16(gAb[i] + k0, lA[i]);
    } else {
#pragma unroll
      for (int i = 0; i < 3; ++i) {
        const float4 x0 = *(const float4*)(gAf[i] + k0);
        const float4 x1 = *(const float4*)(gAf[i] + k0 + 4);
        float v[8] = {x0.x, x0.y, x0.z, x0.w, x1.x, x1.y, x1.z, x1.w};
        if (ASRC == 2) {
          const float4 y0 = *(const float4*)(gAf2[i] + k0);
          const float4 y1 = *(const float4*)(gAf2[i] + k0 + 4);
          v[0] += y0.x; v[1] += y0.y; v[2] += y0.z; v[3] += y0.w;
          v[4] += y1.x; v[5] += y1.y; v[6] += y1.z; v[7] += y1.w;
        }
        ushort_t t[8];
#pragma unroll
        for (int e = 0; e < 8; ++e) t[e] = f2bf(v[e]);
        *(short8*)lA[i] = *(const short8*)t;
      }
    }
    // ---- stage B (fp32 -> bf16 inline) ----
#pragma unroll
    for (int j = 0; j < 4; ++j) {
      const float4 x0 = *(const float4*)(gBf[j] + k0);
      const float4 x1 = *(const float4*)(gBf[j] + k0 + 4);
      ushort_t t[8] = {f2bf(x0.x), f2bf(x0.y), f2bf(x0.z), f2bf(x0.w),
                       f2bf(x1.x), f2bf(x1.y), f2bf(x1.z), f2bf(x1.w)};
      *(short8*)lBf[j] = *(const short8*)t;
    }
    __syncthreads();

#pragma unroll
    for (int k32 = 0; k32 < 2; ++k32) {
      const int cx = ((k32 * 4 + quad) ^ l8) * 8;
      short8 a[3], b[4];
#pragma unroll
      for (int mi = 0; mi < 3; ++mi)
        a[mi] = *(const short8*)&As[(wm * 48 + mi * 16 + l16) * 64 + cx];
#pragma unroll
      for (int ni = 0; ni < 4; ++ni)
        b[ni] = *(const short8*)&Bs[(wn * 64 + ni * 16 + l16) * 64 + cx];
#pragma unroll
      for (int mi = 0; mi < 3; ++mi)
#pragma unroll
        for (int ni = 0; ni < 4; ++ni)
          acc[mi][ni] = __builtin_amdgcn_mfma_f32_16x16x32_bf16(a[mi], b[ni], acc[mi][ni], 0, 0, 0);
    }
    __syncthreads();
  }

  if (MODE == 0) {
    float* C = (float*)C1;
#pragma unroll
    for (int ni = 0; ni < 4; ++ni) {
      const int col = n0 + wn * 64 + ni * 16 + l16;
      const float bia = b1[col];
#pragma unroll
      for (int mi = 0; mi < 3; ++mi) {
        const int rr = m0 + wm * 48 + mi * 16 + quad * 4;
#pragma unroll
        for (int r = 0; r < 4; ++r)
          C[(size_t)(rr + r) * N + col] = acc[mi][ni][r] + bia;
      }
    }
  } else if (MODE == 1) {
    ushort_t* C = (ushort_t*)C1;
#pragma unroll
    for (int ni = 0; ni < 4; ++ni) {
      const int col = n0 + wn * 64 + ni * 16 + l16;
      const float bia = b1[col];
      const int h = col >> 5, ch = col & 31;
#pragma unroll
      for (int mi = 0; mi < 3; ++mi) {
        const int rr = m0 + wm * 48 + mi * 16 + quad * 4;
#pragma unroll
        for (int r = 0; r < 4; ++r)
          C[((size_t)h * QSEQ + rr + r) * 32 + ch] = f2bf(acc[mi][ni][r] + bia);
      }
    }
  } else {
    // MODE 2: cols [0,96) -> LDS logits (only bx==0 has them), then softmax;
    //         cols [96,288) -> C2 fp32 [Q,192]
    float* smf = (float*)smem;  // 96x96 fp32, reuses As/Bs
#pragma unroll
    for (int ni = 0; ni < 4; ++ni) {
      const int col = n0 + wn * 64 + ni * 16 + l16;
      if (col < 96) {
        const float bia = b1[col];
#pragma unroll
        for (int mi = 0; mi < 3; ++mi) {
          const int lr = wm * 48 + mi * 16 + quad * 4;
#pragma unroll
          for (int r = 0; r < 4; ++r)
            smf[(lr + r) * 96 + col] = acc[mi][ni][r] + bia;
        }
      } else if (col < 288) {
        const float bia = b2[col - 96];
#pragma unroll
        for (int mi = 0; mi < 3; ++mi) {
          const int rr = m0 + wm * 48 + mi * 16 + quad * 4;
#pragma unroll
          for (int r = 0; r < 4; ++r)
            C2[(size_t)(rr + r) * 192 + (col - 96)] = acc[mi][ni][r] + bia;
        }
      }
    }
    __syncthreads();
    if (bx == 0) {
      float* C = (float*)C1;
#pragma unroll
      for (int p = 0; p < 3; ++p) {
        const int task = tid + p * 256;  // 768 = 96 rows x 8 heads
        const int row = task >> 3, hh = task & 7;
        float v[12];
        float mx = -1e30f;
#pragma unroll
        for (int i = 0; i < 12; ++i) {
          v[i] = smf[row * 96 + hh * 12 + i];
          mx = fmaxf(mx, v[i]);
        }
        float s = 0.f;
#pragma unroll
        for (int i = 0; i < 12; ++i) {
          v[i] = __expf(v[i] - mx);
          s += v[i];
        }
        const float inv = 1.f / s;
        float4 o[3];
#pragma unroll
        for (int i = 0; i < 3; ++i) {
          o[i].x = v[i * 4 + 0] * inv;
          o[i].y = v[i * 4 + 1] * inv;
          o[i].z = v[i * 4 + 2] * inv;
          o[i].w = v[i * 4 + 3] * inv;
        }
        float4* dst = (float4*)&C[(size_t)(m0 + row) * 96 + hh * 12];
        dst[0] = o[0];
        dst[1] = o[1];
        dst[2] = o[2];
      }
    }
  }
}

// ---------------------------------------------------------------------------
// ONE dispatch for both independent pre-sampler GEMMs: grid (5, 350).
// x in [0,2): value = bf16(ehs) @ Wv^T + bv -> head-major bf16
// x in [2,5): merged hs=(hidden+pos) @ [Wa;Ws]^T -> softmax attn + sp
// ---------------------------------------------------------------------------
__global__ __launch_bounds__(256) void pre_gemms(
    const float* __restrict__ ehs, const float* __restrict__ hidden,
    const float* __restrict__ pos,
    const float* __restrict__ Wv, const float* __restrict__ bv,
    const float* __restrict__ Wa, const float* __restrict__ ba,
    const float* __restrict__ Ws, const float* __restrict__ bs,
    ushort_t* __restrict__ value, float* __restrict__ attn,
    float* __restrict__ sp) {
  extern __shared__ ushort_t smem[];
  if (blockIdx.x < 2)
    gemm_body<1, 1>(blockIdx.x, blockIdx.y, ehs, nullptr, nullptr,
                    Wv, Wv, 1 << 30, bv, nullptr, value, nullptr, 256, smem);
  else
    gemm_body<2, 2>(blockIdx.x - 2, blockIdx.y, hidden, pos, nullptr,
                    Wa, Ws, 96, ba, bs, attn, sp, 288, smem);
}

// ---------------------------------------------------------------------------
// out = sampled(bf16) @ Wo^T + bo -> fp32, grid (2, 350)
// ---------------------------------------------------------------------------
__global__ __launch_bounds__(256) void out_gemm(
    const ushort_t* __restrict__ samp, const float* __restrict__ Wo,
    const float* __restrict__ bo, float* __restrict__ out) {
  extern __shared__ ushort_t smem[];
  gemm_body<0, 0>(blockIdx.x, blockIdx.y, nullptr, nullptr, samp,
                  Wo, Wo, 1 << 30, bo, nullptr, out, nullptr, 256, smem);
}

// ---------------------------------------------------------------------------
// Sampling + aggregation, restructured (round 6):
//   block = 32 tasks (4 q x 8 heads), 256 threads, grid 8400.
//   Phase 1: 384 (task,pt) items, 1 thread each -> LDS table of 48 rows/task:
//            {f32 weight (attn-folded, oob-zeroed), u32 byte offset}.
//            Task stride 100 words (400 B): phase-2 ds_read_b64 of the 8
//            task-groups in a wave hit distinct banks (4t+2r mod 32).
//   Phase 2: wave = 1 q; lane = (h = lane>>3, cgrp = lane&7 -> 4 channels).
//            Each lane serially accumulates 48 weighted uint2 (4ch bf16) rows
//            -> no cross-lane reduce, no dead lanes, coalesced 512B/wave store.
// ---------------------------------------------------------------------------
__global__ __launch_bounds__(256) void msda_sample_kernel(
    const ushort_t* __restrict__ value,  // [8][QSEQ][32] bf16
    const float* __restrict__ sp,        // [Q, 192]
    const float* __restrict__ attn,      // [Q, 96]
    const float* __restrict__ refp,      // [Q, 3, 2]
    ushort_t* __restrict__ outp) {       // [Q, 256] bf16
  __shared__ unsigned wtab[32 * 100];  // 12.8 KB
  const int tid = threadIdx.x;
  const int qbase = blockIdx.x * 4;

  // ---- phase 1: weights + tap offsets, full lane efficiency ----
#pragma unroll
  for (int pass = 0; pass < 2; ++pass) {
    const int it = tid + pass * 256;
    if (it < 384) {
      const int task = it / 12;
      const int pt = it - task * 12;
      const int q = qbase + (task >> 3);
      const int h = task & 7;
      const int lvl = pt >> 2;
      const int S = lvl == 0 ? 160 : (lvl == 1 ? 80 : 40);
      const int base = lvl == 0 ? 0 : (lvl == 1 ? 25600 : 32000);

      const float a = attn[q * 96 + h * 12 + pt];
      const float2 off = *(const float2*)&sp[q * 192 + h * 24 + pt * 2];
      const float2 rp = *(const float2*)&refp[q * 6 + lvl * 2];

      const float x = fmaf(rp.x, (float)S, off.x) - 0.5f;
      const float y = fmaf(rp.y, (float)S, off.y) - 0.5f;
      const float xf = floorf(x), yf = floorf(y);
      const int x0 = (int)xf, y0 = (int)yf;
      const float wx1 = x - xf, wy1 = y - yf;

      const float wx0z = (x0 >= 0 && x0 < S) ? 1.f - wx1 : 0.f;
      const float wx1z = (x0 + 1 >= 0 && x0 + 1 < S) ? wx1 : 0.f;
      const float wy0z = (y0 >= 0 && y0 < S) ? 1.f - wy1 : 0.f;
      const float wy1z = (y0 + 1 >= 0 && y0 + 1 < S) ? wy1 : 0.f;

      const int x0c = min(max(x0, 0), S - 1);
      const int x1c = min(max(x0 + 1, 0), S - 1);
      const int y0c = min(max(y0, 0), S - 1);
      const int y1c = min(max(y0 + 1, 0), S - 1);

      const int r0 = base + y0c * S, r1 = base + y1c * S;
      uint4 e0, e1;
      e0.x = __float_as_uint(a * wx0z * wy0z);
      e0.y = (unsigned)(r0 + x0c) << 6;
      e0.z = __float_as_uint(a * wx1z * wy0z);
      e0.w = (unsigned)(r0 + x1c) << 6;
      e1.x = __float_as_uint(a * wx0z * wy1z);
      e1.y = (unsigned)(r1 + x0c) << 6;
      e1.z = __float_as_uint(a * wx1z * wy1z);
      e1.w = (unsigned)(r1 + x1c) << 6;
      unsigned* dst = &wtab[task * 100 + pt * 8];
      *(uint4*)dst = e0;
      *(uint4*)(dst + 4) = e1;
    }
  }
  __syncthreads();

  // ---- phase 2: per-lane serial accumulation over 48 rows ----
  const int wv = tid >> 6;             // q within block
  const int h = (tid >> 3) & 7;        // head
  const int c = tid & 7;               // channel group (4 ch)
  const int q = qbase + wv;
  const unsigned* wt = &wtab[(wv * 8 + h) * 100];
  const char* vbase = (const char*)value + ((size_t)h * QSEQ) * 64 + c * 8;

  float f0 = 0.f, f1 = 0.f, f2 = 0.f, f3 = 0.f;
#pragma unroll
  for (int r = 0; r < 48; ++r) {
    const uint2 e = *(const uint2*)&wt[r * 2];  // ds_read_b64, imm offset
    const float w = __uint_as_float(e.x);
    const uint2 v = *(const uint2*)(vbase + e.y);
    f0 = fmaf(__uint_as_float(v.x << 16), w, f0);
    f1 = fmaf(__uint_as_float(v.x & 0xFFFF0000u), w, f1);
    f2 = fmaf(__uint_as_float(v.y << 16), w, f2);
    f3 = fmaf(__uint_as_float(v.y & 0xFFFF0000u), w, f3);
  }

  ushort_t t[4] = {f2bf(f0), f2bf(f1), f2bf(f2), f2bf(f3)};
  *(uint2*)&outp[(size_t)q * 256 + h * 32 + c * 4] = *(const uint2*)t;
}

extern "C" void kernel_launch(void* const* d_in, const int* in_sizes, int n_in,
                              void* d_out, int out_size, void* d_ws, size_t ws_size,
                              hipStream_t stream) {
  const float* hidden = (const float*)d_in[0];
  const float* ehs    = (const float*)d_in[1];
  const float* pos    = (const float*)d_in[2];
  const float* refp   = (const float*)d_in[3];
  const float* Wv = (const float*)d_in[4];
  const float* bv = (const float*)d_in[5];
  const float* Ws = (const float*)d_in[6];
  const float* bs = (const float*)d_in[7];
  const float* Wa = (const float*)d_in[8];
  const float* ba = (const float*)d_in[9];
  const float* Wo = (const float*)d_in[10];
  const float* bo = (const float*)d_in[11];

  float* out  = (float*)d_out;             // [Q, 256]
  float* attn = out + (size_t)QSEQ * 256;  // [Q, 96]

  char* ws = (char*)d_ws;
  ushort_t* ws_value = (ushort_t*)ws;                  // [8][Q][32] bf16
  ushort_t* ws_outp  = ws_value + (size_t)QSEQ * 256;  // [Q,256] bf16 sampled
  float* ws_sp = (float*)(ws_outp + (size_t)QSEQ * 256);  // [Q,192] fp32

  dim3 blk(256);

  // 1. both pre-sampler GEMMs in ONE dispatch (independent work, 1750 blocks)
  pre_gemms<<<dim3(5, 350), blk, 36864, stream>>>(
      ehs, hidden, pos, Wv, bv, Wa, ba, Ws, bs, ws_value, attn, ws_sp);
  // 2. sampling (block = 4 q x 8 heads, two-phase)
  msda_sample_kernel<<<dim3(QSEQ / 4), blk, 0, stream>>>(
      ws_value, ws_sp, attn, refp, ws_outp);
  // 3. output projection
  out_gemm<<<dim3(2, 350), blk, 28672, stream>>>(ws_outp, Wo, bo, out);
}

// Round 2
// 268.986 us; speedup vs baseline: 1.1011x; 1.0737x over previous
//
#include <hip/hip_runtime.h>
#include <math.h>

#define QSEQ 33600

typedef __attribute__((ext_vector_type(8))) short short8;
typedef __attribute__((ext_vector_type(4))) float floatx4;
typedef unsigned short ushort_t;

static __device__ __forceinline__ ushort_t f2bf(float f) {
  unsigned u = __float_as_uint(f);
  return (ushort_t)((u + 0x7FFF + ((u >> 16) & 1)) >> 16);
}

// async global->LDS, 16B per lane; lds dest = wave-uniform base + lane*16
static __device__ __forceinline__ void gload_lds16(const void* g, void* l) {
  __builtin_amdgcn_global_load_lds((__attribute__((address_space(1))) void*)g,
                                   (__attribute__((address_space(3))) void*)l, 16, 0, 0);
}

// ---------------------------------------------------------------------------
// MFMA GEMM body, BM=96 (33600 = 350*96), BN=128, BK=64, K=256.
// 256 thr = 4 waves (2x2), wave tile 48x64 (3x4 frags of 16x16x32 bf16).
// LDS: As 96x64 bf16 | Bs 128x64 bf16, chunk-XOR swizzle (slot (row,s) holds
// global 16B-chunk s^(row&7)).
// B is staged from *fp32* weights with inline bf16 convert (no pre-pass).
// B row select: global row < bsplit -> B1[row], else B2[row-bsplit] (clamped).
// ASRC: 0 = A bf16 via global_load_lds; 1 = A fp32 cvt; 2 = fp32 A1+A2 add.
// MODE: 0 = fp32 C1[M,N]; 1 = bf16 head-major [col>>5][row][col&31];
//       2 = N=288 merged: cols<96 logits -> fused softmax -> C1 [Q,96] fp32,
//           cols [96,288) -> C2 [Q,192] fp32 (+b2).
// ---------------------------------------------------------------------------
template <int ASRC, int MODE>
static __device__ __forceinline__ void gemm_body(
    const int bx, const int by,
    const float* __restrict__ A1, const float* __restrict__ A2,
    const ushort_t* __restrict__ Ab,
    const float* __restrict__ B1, const float* __restrict__ B2, const int bsplit,
    const float* __restrict__ b1, const float* __restrict__ b2,
    void* __restrict__ C1, float* __restrict__ C2, const int N,
    ushort_t* smem) {
  ushort_t* As = smem;         // 6144 ushorts
  ushort_t* Bs = smem + 6144;  // 8192 ushorts

  const int tid = threadIdx.x;
  const int m0 = by * 96;
  const int n0 = bx * 128;
  const int wv = tid >> 6, lane = tid & 63;
  const int wm = wv >> 1, wn = wv & 1;
  const int l16 = lane & 15, quad = lane >> 4;
  const int l8 = l16 & 7;

  // --- A staging descriptors: 768 chunks (96 rows x 8), 3 per thread ---
  const float* gAf[3];
  const float* gAf2[3];
  const ushort_t* gAb[3];
  ushort_t* lA[3];
#pragma unroll
  for (int i = 0; i < 3; ++i) {
    const int c = tid + i * 256;
    const int row = c >> 3, s = c & 7;
    if (ASRC == 0) {
      gAb[i] = Ab + (size_t)(m0 + row) * 256 + ((s ^ (row & 7)) * 8);
      lA[i] = As + (wv * 64 + i * 256) * 8;  // wave-uniform base, lane-linear
    } else {
      gAf[i] = A1 + (size_t)(m0 + row) * 256 + s * 8;
      if (ASRC == 2) gAf2[i] = A2 + (size_t)(m0 + row) * 256 + s * 8;
      lA[i] = As + row * 64 + (s ^ (row & 7)) * 8;
    }
  }
  // --- B staging: 1024 chunks (128 rows x 8), 4 per thread, fp32 src ---
  const float* gBf[4];
  ushort_t* lBf[4];
#pragma unroll
  for (int j = 0; j < 4; ++j) {
    const int c = tid + j * 256;
    const int row = c >> 3, s = c & 7;
    const int grow = n0 + row;
    const float* bsrc;
    int r2;
    if (grow < bsplit) {
      bsrc = B1;
      r2 = grow;
    } else {
      bsrc = B2;
      r2 = grow - bsplit;
      const int rmax = N - bsplit - 1;
      if (r2 > rmax) r2 = rmax;  // clamp: garbage cols, stores guarded
    }
    gBf[j] = bsrc + (size_t)r2 * 256 + s * 8;
    lBf[j] = Bs + row * 64 + (s ^ (row & 7)) * 8;
  }

  floatx4 acc[3][4];
#pragma unroll
  for (int i = 0; i < 3; ++i)
#pragma unroll
    for (int j = 0; j < 4; ++j) acc[i][j] = (floatx4)(0.f);

  for (int k0 = 0; k0 < 256; k0 += 64) {
    // ---- stage A ----
    if (ASRC == 0) {
#pragma unroll
      for (int i = 0; i < 3; ++i) gload_lds16(gAb[i] + k0, lA[i]);
    } else {
#pragma unroll
      for (int i = 0; i < 3; ++i) {
        const float4 x0 = *(const float4*)(gAf[i] + k0);
        const float4 x1 = *(const float4*)(gAf[i] + k0 + 4);
        float v[8] = {x0.x, x0.y, x0.z, x0.w, x1.x, x1.y, x1.z, x1.w};
        if (ASRC == 2) {
          const float4 y0 = *(const float4*)(gAf2[i] + k0);
          const float4 y1 = *(const float4*)(gAf2[i] + k0 + 4);
          v[0] += y0.x; v[1] += y0.y; v[2] += y0.z; v[3] += y0.w;
          v[4] += y1.x; v[5] += y1.y; v[6] += y1.z; v[7] += y1.w;
        }
        ushort_t t[8];
#pragma unroll
        for (int e = 0; e < 8; ++e) t[e] = f2bf(v[e]);
        *(short8*)lA[i] = *(const short8*)t;
      }
    }
    // ---- stage B (fp32 -> bf16 inline) ----
#pragma unroll
    for (int j = 0; j < 4; ++j) {
      const float4 x0 = *(const float4*)(gBf[j] + k0);
      const float4 x1 = *(const float4*)(gBf[j] + k0 + 4);
      ushort_t t[8] = {f2bf(x0.x), f2bf(x0.y), f2bf(x0.z), f2bf(x0.w),
                       f2bf(x1.x), f2bf(x1.y), f2bf(x1.z), f2bf(x1.w)};
      *(short8*)lBf[j] = *(const short8*)t;
    }
    __syncthreads();

#pragma unroll
    for (int k32 = 0; k32 < 2; ++k32) {
      const int cx = ((k32 * 4 + quad) ^ l8) * 8;
      short8 a[3], b[4];
#pragma unroll
      for (int mi = 0; mi < 3; ++mi)
        a[mi] = *(const short8*)&As[(wm * 48 + mi * 16 + l16) * 64 + cx];
#pragma unroll
      for (int ni = 0; ni < 4; ++ni)
        b[ni] = *(const short8*)&Bs[(wn * 64 + ni * 16 + l16) * 64 + cx];
#pragma unroll
      for (int mi = 0; mi < 3; ++mi)
#pragma unroll
        for (int ni = 0; ni < 4; ++ni)
          acc[mi][ni] = __builtin_amdgcn_mfma_f32_16x16x32_bf16(a[mi], b[ni], acc[mi][ni], 0, 0, 0);
    }
    __syncthreads();
  }

  if (MODE == 0) {
    float* C = (float*)C1;
#pragma unroll
    for (int ni = 0; ni < 4; ++ni) {
      const int col = n0 + wn * 64 + ni * 16 + l16;
      const float bia = b1[col];
#pragma unroll
      for (int mi = 0; mi < 3; ++mi) {
        const int rr = m0 + wm * 48 + mi * 16 + quad * 4;
#pragma unroll
        for (int r = 0; r < 4; ++r)
          C[(size_t)(rr + r) * N + col] = acc[mi][ni][r] + bia;
      }
    }
  } else if (MODE == 1) {
    ushort_t* C = (ushort_t*)C1;
#pragma unroll
    for (int ni = 0; ni < 4; ++ni) {
      const int col = n0 + wn * 64 + ni * 16 + l16;
      const float bia = b1[col];
      const int h = col >> 5, ch = col & 31;
#pragma unroll
      for (int mi = 0; mi < 3; ++mi) {
        const int rr = m0 + wm * 48 + mi * 16 + quad * 4;
#pragma unroll
        for (int r = 0; r < 4; ++r)
          C[((size_t)h * QSEQ + rr + r) * 32 + ch] = f2bf(acc[mi][ni][r] + bia);
      }
    }
  } else {
    // MODE 2: cols [0,96) -> LDS logits (only bx==0 has them), then softmax;
    //         cols [96,288) -> C2 fp32 [Q,192]
    float* smf = (float*)smem;  // 96x96 fp32, reuses As/Bs
#pragma unroll
    for (int ni = 0; ni < 4; ++ni) {
      const int col = n0 + wn * 64 + ni * 16 + l16;
      if (col < 96) {
        const float bia = b1[col];
#pragma unroll
        for (int mi = 0; mi < 3; ++mi) {
          const int lr = wm * 48 + mi * 16 + quad * 4;
#pragma unroll
          for (int r = 0; r < 4; ++r)
            smf[(lr + r) * 96 + col] = acc[mi][ni][r] + bia;
        }
      } else if (col < 288) {
        const float bia = b2[col - 96];
#pragma unroll
        for (int mi = 0; mi < 3; ++mi) {
          const int rr = m0 + wm * 48 + mi * 16 + quad * 4;
#pragma unroll
          for (int r = 0; r < 4; ++r)
            C2[(size_t)(rr + r) * 192 + (col - 96)] = acc[mi][ni][r] + bia;
        }
      }
    }
    __syncthreads();
    if (bx == 0) {
      float* C = (float*)C1;
#pragma unroll
      for (int p = 0; p < 3; ++p) {
        const int task = tid + p * 256;  // 768 = 96 rows x 8 heads
        const int row = task >> 3, hh = task & 7;
        float v[12];
        float mx = -1e30f;
#pragma unroll
        for (int i = 0; i < 12; ++i) {
          v[i] = smf[row * 96 + hh * 12 + i];
          mx = fmaxf(mx, v[i]);
        }
        float s = 0.f;
#pragma unroll
        for (int i = 0; i < 12; ++i) {
          v[i] = __expf(v[i] - mx);
          s += v[i];
        }
        const float inv = 1.f / s;
        float4 o[3];
#pragma unroll
        for (int i = 0; i < 3; ++i) {
          o[i].x = v[i * 4 + 0] * inv;
          o[i].y = v[i * 4 + 1] * inv;
          o[i].z = v[i * 4 + 2] * inv;
          o[i].w = v[i * 4 + 3] * inv;
        }
        float4* dst = (float4*)&C[(size_t)(m0 + row) * 96 + hh * 12];
        dst[0] = o[0];
        dst[1] = o[1];
        dst[2] = o[2];
      }
    }
  }
}

// ---------------------------------------------------------------------------
// ONE dispatch for both independent pre-sampler GEMMs: grid (5, 350).
// x in [0,2): value = bf16(ehs) @ Wv^T + bv -> head-major bf16
// x in [2,5): merged hs=(hidden+pos) @ [Wa;Ws]^T -> softmax attn + sp
// ---------------------------------------------------------------------------
__global__ __launch_bounds__(256) void pre_gemms(
    const float* __restrict__ ehs, const float* __restrict__ hidden,
    const float* __restrict__ pos,
    const float* __restrict__ Wv, const float* __restrict__ bv,
    const float* __restrict__ Wa, const float* __restrict__ ba,
    const float* __restrict__ Ws, const float* __restrict__ bs,
    ushort_t* __restrict__ value, float* __restrict__ attn,
    float* __restrict__ sp) {
  extern __shared__ ushort_t smem[];
  if (blockIdx.x < 2)
    gemm_body<1, 1>(blockIdx.x, blockIdx.y, ehs, nullptr, nullptr,
                    Wv, Wv, 1 << 30, bv, nullptr, value, nullptr, 256, smem);
  else
    gemm_body<2, 2>(blockIdx.x - 2, blockIdx.y, hidden, pos, nullptr,
                    Wa, Ws, 96, ba, bs, attn, sp, 288, smem);
}

// ---------------------------------------------------------------------------
// out = sampled(bf16) @ Wo^T + bo -> fp32, grid (2, 350)
// ---------------------------------------------------------------------------
__global__ __launch_bounds__(256) void out_gemm(
    const ushort_t* __restrict__ samp, const float* __restrict__ Wo,
    const float* __restrict__ bo, float* __restrict__ out) {
  extern __shared__ ushort_t smem[];
  gemm_body<0, 0>(blockIdx.x, blockIdx.y, nullptr, nullptr, samp,
                  Wo, Wo, 1 << 30, bo, nullptr, out, nullptr, 256, smem);
}

// ---------------------------------------------------------------------------
// Sampling + aggregation (round 7): two-phase structure from round 6, but
// block = 32 q x ONE head (grid 1050*8, h = blockIdx.x & 7) so each XCD's
// L2 stays on a single 2.15MB head plane (round-6 all-heads blocks
// oversubscribed the 4MB per-XCD L2 4x -> FETCH_SIZE 276MB).
//   Phase 1: 384 (q,pt) items, 1 thread each -> LDS: 48 rows/q of
//            {f32 weight (attn-folded, oob-zeroed), u32 byte offset}.
//            q stride 100 words (400B) -> phase-2 reads bank-conflict-free.
//   Phase 2: wave = 8 q x 8 channel-groups (4 ch each, uint2 loads); each
//            lane serially accumulates 48 weighted rows; no cross-lane
//            reduce, no dead lanes; coalesced 64B/q stores.
// ---------------------------------------------------------------------------
__global__ __launch_bounds__(256) void msda_sample_kernel(
    const ushort_t* __restrict__ value,  // [8][QSEQ][32] bf16
    const float* __restrict__ sp,        // [Q, 192]
    const float* __restrict__ attn,      // [Q, 96]
    const float* __restrict__ refp,      // [Q, 3, 2]
    ushort_t* __restrict__ outp) {       // [Q, 256] bf16
  __shared__ unsigned wtab[32 * 100];  // 12.8 KB
  const int tid = threadIdx.x;
  const int h = blockIdx.x & 7;            // XCD-affine head
  const int qbase = (blockIdx.x >> 3) * 32;

  // ---- phase 1: weights + tap offsets, full lane efficiency ----
#pragma unroll
  for (int pass = 0; pass < 2; ++pass) {
    const int it = tid + pass * 256;
    if (it < 384) {
      const int tq = it / 12;        // q within block
      const int pt = it - tq * 12;
      const int q = qbase + tq;
      const int lvl = pt >> 2;
      const int S = lvl == 0 ? 160 : (lvl == 1 ? 80 : 40);
      const int base = lvl == 0 ? 0 : (lvl == 1 ? 25600 : 32000);

      const float a = attn[q * 96 + h * 12 + pt];
      const float2 off = *(const float2*)&sp[q * 192 + h * 24 + pt * 2];
      const float2 rp = *(const float2*)&refp[q * 6 + lvl * 2];

      const float x = fmaf(rp.x, (float)S, off.x) - 0.5f;
      const float y = fmaf(rp.y, (float)S, off.y) - 0.5f;
      const float xf = floorf(x), yf = floorf(y);
      const int x0 = (int)xf, y0 = (int)yf;
      const float wx1 = x - xf, wy1 = y - yf;

      const float wx0z = (x0 >= 0 && x0 < S) ? 1.f - wx1 : 0.f;
      const float wx1z = (x0 + 1 >= 0 && x0 + 1 < S) ? wx1 : 0.f;
      const float wy0z = (y0 >= 0 && y0 < S) ? 1.f - wy1 : 0.f;
      const float wy1z = (y0 + 1 >= 0 && y0 + 1 < S) ? wy1 : 0.f;

      const int x0c = min(max(x0, 0), S - 1);
      const int x1c = min(max(x0 + 1, 0), S - 1);
      const int y0c = min(max(y0, 0), S - 1);
      const int y1c = min(max(y0 + 1, 0), S - 1);

      const int r0 = base + y0c * S, r1 = base + y1c * S;
      uint4 e0, e1;
      e0.x = __float_as_uint(a * wx0z * wy0z);
      e0.y = (unsigned)(r0 + x0c) << 6;
      e0.z = __float_as_uint(a * wx1z * wy0z);
      e0.w = (unsigned)(r0 + x1c) << 6;
      e1.x = __float_as_uint(a * wx0z * wy1z);
      e1.y = (unsigned)(r1 + x0c) << 6;
      e1.z = __float_as_uint(a * wx1z * wy1z);
      e1.w = (unsigned)(r1 + x1c) << 6;
      unsigned* dst = &wtab[tq * 100 + pt * 8];
      *(uint4*)dst = e0;
      *(uint4*)(dst + 4) = e1;
    }
  }
  __syncthreads();

  // ---- phase 2: per-lane serial accumulation over 48 rows ----
  const int wv = tid >> 6;             // wave -> q octet
  const int qi = (tid >> 3) & 7;       // q within octet
  const int c = tid & 7;               // channel group (4 ch)
  const int tq = wv * 8 + qi;
  const int q = qbase + tq;
  const unsigned* wt = &wtab[tq * 100];
  const char* vbase = (const char*)value + ((size_t)h * QSEQ) * 64 + c * 8;

  float f0 = 0.f, f1 = 0.f, f2 = 0.f, f3 = 0.f;
#pragma unroll
  for (int r = 0; r < 48; ++r) {
    const uint2 e = *(const uint2*)&wt[r * 2];  // ds_read_b64, imm offset
    const float w = __uint_as_float(e.x);
    const uint2 v = *(const uint2*)(vbase + e.y);
    f0 = fmaf(__uint_as_float(v.x << 16), w, f0);
    f1 = fmaf(__uint_as_float(v.x & 0xFFFF0000u), w, f1);
    f2 = fmaf(__uint_as_float(v.y << 16), w, f2);
    f3 = fmaf(__uint_as_float(v.y & 0xFFFF0000u), w, f3);
  }

  ushort_t t[4] = {f2bf(f0), f2bf(f1), f2bf(f2), f2bf(f3)};
  *(uint2*)&outp[(size_t)q * 256 + h * 32 + c * 4] = *(const uint2*)t;
}

extern "C" void kernel_launch(void* const* d_in, const int* in_sizes, int n_in,
                              void* d_out, int out_size, void* d_ws, size_t ws_size,
                              hipStream_t stream) {
  const float* hidden = (const float*)d_in[0];
  const float* ehs    = (const float*)d_in[1];
  const float* pos    = (const float*)d_in[2];
  const float* refp   = (const float*)d_in[3];
  const float* Wv = (const float*)d_in[4];
  const float* bv = (const float*)d_in[5];
  const float* Ws = (const float*)d_in[6];
  const float* bs = (const float*)d_in[7];
  const float* Wa = (const float*)d_in[8];
  const float* ba = (const float*)d_in[9];
  const float* Wo = (const float*)d_in[10];
  const float* bo = (const float*)d_in[11];

  float* out  = (float*)d_out;             // [Q, 256]
  float* attn = out + (size_t)QSEQ * 256;  // [Q, 96]

  char* ws = (char*)d_ws;
  ushort_t* ws_value = (ushort_t*)ws;                  // [8][Q][32] bf16
  ushort_t* ws_outp  = ws_value + (size_t)QSEQ * 256;  // [Q,256] bf16 sampled
  float* ws_sp = (float*)(ws_outp + (size_t)QSEQ * 256);  // [Q,192] fp32

  dim3 blk(256);

  // 1. both pre-sampler GEMMs in ONE dispatch (independent work, 1750 blocks)
  pre_gemms<<<dim3(5, 350), blk, 36864, stream>>>(
      ehs, hidden, pos, Wv, bv, Wa, ba, Ws, bs, ws_value, attn, ws_sp);
  // 2. sampling (block = 32 q x 1 head, two-phase, XCD-affine heads)
  msda_sample_kernel<<<dim3((QSEQ / 32) * 8), blk, 0, stream>>>(
      ws_value, ws_sp, attn, refp, ws_outp);
  // 3. output projection
  out_gemm<<<dim3(2, 350), blk, 28672, stream>>>(ws_outp, Wo, bo, out);
}